// Round 6
// baseline (259.643 us; speedup 1.0000x reference)
//
#include <hip/hip_runtime.h>
#include <cmath>

#define TBL_SIZE (1u << 19)
#define TBL_MASK (TBL_SIZE - 1u)
#define PRIME1 2654435761u
#define PRIME2 805459861u
#define NUM_LEVELS 16
#define HARD0 6          // levels >= 6 have ~4MB (f32) / 2MB (bf16) hot footprint
#define PPB 32           // points per 256-thread block (8 lanes per point)

struct ScaleArgs { float s[NUM_LEVELS]; };

typedef float v2f __attribute__((ext_vector_type(2)));

// v + dpp_mov<CTRL>(v) — pure-VALU cross-lane add.
template<int CTRL>
__device__ __forceinline__ float dpp_add(float v) {
    int i = __builtin_bit_cast(int, v);
    int j = __builtin_amdgcn_mov_dpp(i, CTRL, 0xF, 0xF, true);
    return v + __builtin_bit_cast(float, j);
}

// f32 -> bf16 with round-to-nearest-even (data has no NaN/Inf).
__device__ __forceinline__ uint32_t f2bf(float f) {
    uint32_t u = __builtin_bit_cast(uint32_t, f);
    return (u + 0x7FFFu + ((u >> 16) & 1u)) >> 16;
}

// Pack the f32 table into bf16-pair entries (4B each) in ws.
__global__ __launch_bounds__(256) void cvt_table_kernel(
    const float* __restrict__ table, uint32_t* __restrict__ tbl_bf, int nentries)
{
    int gid = blockIdx.x * blockDim.x + threadIdx.x;   // one entry (2 floats) per thread
    if (gid >= nentries) return;
    float2 e = reinterpret_cast<const float2*>(table)[gid];
    tbl_bf[gid] = f2bf(e.x) | (f2bf(e.y) << 16);
}

// Corner-per-lane gather from the packed bf16 table (4B requests).
__global__ __launch_bounds__(256) void HashEncoding_88837103551034_kernel(
    const float* __restrict__ x,
    const uint32_t* __restrict__ tbl_bf,
    float* __restrict__ out,
    int npoints, int CH, int perXcdHard, int hardTotal, int easyTotal,
    ScaleArgs sc)
{
    int b = blockIdx.x;
    int xcd = b & 7;
    int s = b >> 3;

    int level, chunk;
    if (s < perXcdHard) {
        int g = xcd * perXcdHard + s;          // hard levels: contiguous per XCD
        if (g >= hardTotal) return;
        int li = g / CH;
        level = HARD0 + li;
        chunk = g - li * CH;
    } else {
        int g = (s - perXcdHard) * 8 + xcd;    // easy levels: striped
        if (g >= easyTotal) return;
        int li = g / CH;
        level = li;
        chunk = g - li * CH;
    }

    int t = (int)threadIdx.x;
    int corner = t & 7;
    int n = chunk * PPB + (t >> 3);
    if (n >= npoints) return;

    float x0 = x[(size_t)n * 3 + 0] * 0.5f + 0.5f;
    float x1 = x[(size_t)n * 3 + 1] * 0.5f + 0.5f;
    float x2 = x[(size_t)n * 3 + 2] * 0.5f + 0.5f;

    float sl = sc.s[level];
    float sx = x0 * sl, sy = x1 * sl, sz = x2 * sl;
    float fx = floorf(sx), fy = floorf(sy), fz = floorf(sz);
    float ox = sx - fx, oy = sy - fy, oz = sz - fz;

    int bx = (corner >> 2) & 1, by = (corner >> 1) & 1, bz = corner & 1;

    // ceil==floor+1 except integral coords, where the ceil-corner weight is 0.
    uint32_t h = (uint32_t)((int)fx + bx)
               ^ ((uint32_t)((int)fy + by) * PRIME1)
               ^ ((uint32_t)((int)fz + bz) * PRIME2);

    uint32_t v = tbl_bf[(size_t)level * TBL_SIZE + (h & TBL_MASK)];
    float f0 = __builtin_bit_cast(float, v << 16);
    float f1 = __builtin_bit_cast(float, v & 0xFFFF0000u);

    float w = (bx ? ox : 1.f - ox)
            * (by ? oy : 1.f - oy)
            * (bz ? oz : 1.f - oz);

    float e0 = f0 * w;
    float e1 = f1 * w;

    e0 = dpp_add<0xB1>(e0);  e1 = dpp_add<0xB1>(e1);   // quad_perm xor1
    e0 = dpp_add<0x4E>(e0);  e1 = dpp_add<0x4E>(e1);   // quad_perm xor2
    e0 = dpp_add<0x141>(e0); e1 = dpp_add<0x141>(e1);  // row_half_mirror (0<-7)

    if (corner == 0) {
        v2f res; res.x = e0; res.y = e1;
        __builtin_nontemporal_store(res, (v2f*)(out + (size_t)n * (NUM_LEVELS * 2) + level * 2));
    }
}

// Fallback (f32 gathers), used only if ws is too small for the bf16 table.
__global__ __launch_bounds__(256) void hash_f32_kernel(
    const float* __restrict__ x,
    const float* __restrict__ table,
    float* __restrict__ out,
    int npoints, int CH, int perXcdHard, int hardTotal, int easyTotal,
    ScaleArgs sc)
{
    int b = blockIdx.x;
    int xcd = b & 7;
    int s = b >> 3;
    int level, chunk;
    if (s < perXcdHard) {
        int g = xcd * perXcdHard + s;
        if (g >= hardTotal) return;
        int li = g / CH; level = HARD0 + li; chunk = g - li * CH;
    } else {
        int g = (s - perXcdHard) * 8 + xcd;
        if (g >= easyTotal) return;
        int li = g / CH; level = li; chunk = g - li * CH;
    }
    int t = (int)threadIdx.x;
    int corner = t & 7;
    int n = chunk * PPB + (t >> 3);
    if (n >= npoints) return;
    float x0 = x[(size_t)n * 3 + 0] * 0.5f + 0.5f;
    float x1 = x[(size_t)n * 3 + 1] * 0.5f + 0.5f;
    float x2 = x[(size_t)n * 3 + 2] * 0.5f + 0.5f;
    float sl = sc.s[level];
    float sx = x0 * sl, sy = x1 * sl, sz = x2 * sl;
    float fx = floorf(sx), fy = floorf(sy), fz = floorf(sz);
    float ox = sx - fx, oy = sy - fy, oz = sz - fz;
    int bx = (corner >> 2) & 1, by = (corner >> 1) & 1, bz = corner & 1;
    uint32_t h = (uint32_t)((int)fx + bx)
               ^ ((uint32_t)((int)fy + by) * PRIME1)
               ^ ((uint32_t)((int)fz + bz) * PRIME2);
    const float2* tb = reinterpret_cast<const float2*>(table) + (size_t)level * TBL_SIZE;
    float2 f = tb[h & TBL_MASK];
    float w = (bx ? ox : 1.f - ox) * (by ? oy : 1.f - oy) * (bz ? oz : 1.f - oz);
    float e0 = f.x * w, e1 = f.y * w;
    e0 = dpp_add<0xB1>(e0);  e1 = dpp_add<0xB1>(e1);
    e0 = dpp_add<0x4E>(e0);  e1 = dpp_add<0x4E>(e1);
    e0 = dpp_add<0x141>(e0); e1 = dpp_add<0x141>(e1);
    if (corner == 0) {
        v2f res; res.x = e0; res.y = e1;
        __builtin_nontemporal_store(res, (v2f*)(out + (size_t)n * (NUM_LEVELS * 2) + level * 2));
    }
}

extern "C" void kernel_launch(void* const* d_in, const int* in_sizes, int n_in,
                              void* d_out, int out_size, void* d_ws, size_t ws_size,
                              hipStream_t stream) {
    const float* x = (const float*)d_in[0];
    const float* table = (const float*)d_in[1];
    float* out = (float*)d_out;
    int npoints = in_sizes[0] / 3;

    ScaleArgs sc;
    double growth = std::exp((std::log(1024.0) - std::log(16.0)) / 15.0);
    for (int l = 0; l < NUM_LEVELS; ++l) {
        sc.s[l] = (float)std::floor(16.0 * std::pow(growth, (double)l));
    }

    int CH = (npoints + PPB - 1) / PPB;
    int nHard = NUM_LEVELS - HARD0;
    int hardTotal = nHard * CH;
    int easyTotal = HARD0 * CH;
    int perXcdHard = (hardTotal + 7) / 8;
    int perXcdEasy = (easyTotal + 7) / 8;
    int grid = 8 * (perXcdHard + perXcdEasy);

    const int nentries = TBL_SIZE * NUM_LEVELS;              // 8.4M entries
    const size_t need = (size_t)nentries * sizeof(uint32_t); // 32 MB

    if (ws_size >= need) {
        uint32_t* tbl_bf = (uint32_t*)d_ws;
        int cgrid = (nentries + 255) / 256;
        cvt_table_kernel<<<cgrid, 256, 0, stream>>>(table, tbl_bf, nentries);
        HashEncoding_88837103551034_kernel<<<grid, 256, 0, stream>>>(
            x, tbl_bf, out, npoints, CH, perXcdHard, hardTotal, easyTotal, sc);
    } else {
        hash_f32_kernel<<<grid, 256, 0, stream>>>(
            x, table, out, npoints, CH, perXcdHard, hardTotal, easyTotal, sc);
    }
}